// Round 18
// baseline (471.956 us; speedup 1.0000x reference)
//
#include <hip/hip_runtime.h>
#include <cstdio>

#define NN 50000
#define NE 640000
#define NG 256
#define NL 4

#define SCAN_CHUNK 1024
#define NB_SCAN ((NN + SCAN_CHUNK - 1) / SCAN_CHUNK)   // 49

typedef unsigned short u16;
typedef unsigned int u32;
typedef __attribute__((ext_vector_type(8))) short short8v;   // 8 bf16 = 4 VGPR
typedef __attribute__((ext_vector_type(4))) float f32x4;

static __device__ __forceinline__ float bf2f(u16 v) {
    return __uint_as_float(((u32)v) << 16);
}
static __device__ __forceinline__ u16 f2bf(float f) {
    u32 u = __float_as_uint(f);
    u += 0x7fff + ((u >> 16) & 1);   // RNE
    return (u16)(u >> 16);
}

// ---------------- k_deg ----------------
__global__ __launch_bounds__(256) void k_deg(
    const int* __restrict__ rec, int* __restrict__ deg)
{
    const int e = blockIdx.x * 256 + threadIdx.x;
    atomicAdd(&deg[rec[e]], 1);
}

// ---------------- k_prep_xp ----------------
__global__ __launch_bounds__(256) void k_prep_xp(
    const float* __restrict__ x, const float* __restrict__ p,
    u16* __restrict__ Axp)
{
    const int idx = blockIdx.x * 256 + threadIdx.x;   // NN*48 u32s
    const int row = idx / 48;
    const int c2 = idx - row * 48;
    const int c0 = c2 * 2;
    float f0, f1;
    if (c0 < 64)      { f0 = x[(size_t)row * 64 + c0]; f1 = x[(size_t)row * 64 + c0 + 1]; }
    else if (c0 < 80) { f0 = p[(size_t)row * 16 + c0 - 64]; f1 = p[(size_t)row * 16 + c0 - 63]; }
    else              { f0 = 0.f; f1 = 0.f; }
    ((u32*)Axp)[idx] = (u32)f2bf(f0) | ((u32)f2bf(f1) << 16);
}

// ---------------- k_wembed: [ks][col][32] ----------------
__global__ __launch_bounds__(256) void k_wembed(
    const float* __restrict__ W, u16* __restrict__ Wp)
{
    const int idx = blockIdx.x * 256 + threadIdx.x;   // 3*128*32
    const int ks = idx >> 12;
    const int rem = idx & 4095;
    const int col = rem >> 5;
    const int kk = rem & 31;
    const int k = ks * 32 + kk;
    Wp[((size_t)ks * 128 + col) * 32 + kk] = f2bf(k < 80 ? W[k * 128 + col] : 0.f);
}

// ---------------- k_embed ----------------
__global__ __launch_bounds__(256) void k_embed(
    const u16* __restrict__ Axp, const u16* __restrict__ Wp,
    const float* __restrict__ b, u16* __restrict__ h)
{
    const int t = threadIdx.x;
    const int lane = t & 63;
    const int w = t >> 6;
    const int rb = blockIdx.x * 128 + w * 32;
    const int l15 = lane & 15;
    const int kg  = lane >> 4;

    int r0 = rb + l15;      if (r0 > NN - 1) r0 = NN - 1;
    int r1 = rb + 16 + l15; if (r1 > NN - 1) r1 = NN - 1;

    f32x4 acc[2][8];
    #pragma unroll
    for (int m = 0; m < 2; ++m)
        #pragma unroll
        for (int n = 0; n < 8; ++n) acc[m][n] = (f32x4){0.f, 0.f, 0.f, 0.f};

    #pragma unroll
    for (int ks = 0; ks < 3; ++ks) {
        const short8v a0 = *(const short8v*)(Axp + (size_t)r0 * 96 + ks * 32 + kg * 8);
        const short8v a1 = *(const short8v*)(Axp + (size_t)r1 * 96 + ks * 32 + kg * 8);
        const u16* bb = Wp + ((size_t)ks * 128 + l15) * 32 + kg * 8;
        #pragma unroll
        for (int nf = 0; nf < 8; ++nf) {
            const short8v bv = *(const short8v*)(bb + (size_t)nf * 16 * 32);
            acc[0][nf] = __builtin_amdgcn_mfma_f32_16x16x32_bf16(a0, bv, acc[0][nf], 0, 0, 0);
            acc[1][nf] = __builtin_amdgcn_mfma_f32_16x16x32_bf16(a1, bv, acc[1][nf], 0, 0, 0);
        }
    }

    #pragma unroll
    for (int m = 0; m < 2; ++m) {
        #pragma unroll
        for (int r = 0; r < 4; ++r) {
            const int row = rb + m * 16 + kg * 4 + r;
            if (row < NN) {
                #pragma unroll
                for (int nf = 0; nf < 8; ++nf) {
                    const int col = nf * 16 + l15;
                    h[(size_t)row * 128 + col] = f2bf(acc[m][nf][r] + b[col]);
                }
            }
        }
    }
}

// ---------------- k_wprep: Wb fp32 [l][512][256] + cvec ----------------
__global__ __launch_bounds__(256) void k_wprep(
    const float* __restrict__ Wm, const float* __restrict__ Wh,
    const float* __restrict__ We, const float* __restrict__ bm,
    float* __restrict__ Wb, float* __restrict__ cvec)
{
    const int idx = blockIdx.x * 256 + threadIdx.x;
    const int total = 4 * 512 * 256;
    if (idx < total) {
        const int l = idx >> 17;
        const int rem = idx & 131071;
        const int k = rem >> 8;
        const int c = rem & 255;
        const float* Wm_l = Wm + (size_t)l * 384 * 128;
        const float* Wh_l = Wh + (size_t)l * 256 * 128;
        const float* We_l = We + (size_t)l * 384 * 128;
        float v;
        if (k < 128) {
            v = (c < 128) ? Wh_l[k * 128 + c] : 0.f;
        } else {
            const int kk  = (k - 128) & 127;
            const int blk = (k - 128) >> 7;               // 0:dh 1:Sh 2:Se
            const int roff = (blk == 0) ? 128 : (blk == 1) ? 0 : 256;
            if (c < 128) {
                float s = 0.f;
                #pragma unroll 4
                for (int j = 0; j < 128; ++j)
                    s += Wm_l[(roff + kk) * 128 + j] * Wh_l[(128 + j) * 128 + c];
                v = s;
            } else {
                v = We_l[(roff + kk) * 128 + (c - 128)];
            }
        }
        Wb[idx] = v;
    } else if (idx < total + 512) {
        const int r = idx - total;
        const int l = r >> 7;
        const int c = r & 127;
        const float* Wh_l = Wh + (size_t)l * 256 * 128;
        const float* bm_l = bm + l * 128;
        float s = 0.f;
        #pragma unroll 4
        for (int j = 0; j < 128; ++j) s += bm_l[j] * Wh_l[(128 + j) * 128 + c];
        cvec[r] = s;
    }
}

// ---------------- k_wswz: Wb -> Bp bf16 [l][ks][cg64][kg][n64][8] ----------------
__global__ __launch_bounds__(256) void k_wswz(
    const float* __restrict__ Wb, u16* __restrict__ Bp)
{
    const int idx = blockIdx.x * 256 + threadIdx.x;    // 4*512*256
    const int l = idx >> 17;
    const int rem = idx & 131071;
    const int k = rem >> 8;
    const int n = rem & 255;
    const int ks = k >> 5;
    const int kg = (k >> 3) & 3;
    const int kk = k & 7;
    const int cg = n >> 6;
    const int n64 = n & 63;
    Bp[(size_t)l * 131072 +
       ((((size_t)ks * 4 + cg) * 4 + kg) * 64 + n64) * 8 + kk] = f2bf(Wb[idx]);
}

// ---------------- scan (3 phases) ----------------
__global__ __launch_bounds__(256) void k_scanA(
    const int* __restrict__ deg, int* __restrict__ part)
{
    __shared__ int red[256];
    const int t = threadIdx.x;
    const int base = blockIdx.x * SCAN_CHUNK + t * 4;
    int s = 0;
    #pragma unroll
    for (int i = 0; i < 4; ++i) {
        const int idx = base + i;
        if (idx < NN) s += deg[idx];
    }
    red[t] = s;
    __syncthreads();
    for (int off = 128; off > 0; off >>= 1) {
        if (t < off) red[t] += red[t + off];
        __syncthreads();
    }
    if (t == 0) part[blockIdx.x] = red[0];
}

__global__ __launch_bounds__(64) void k_scanB(int* part)
{
    if (threadIdx.x == 0) {
        int run = 0;
        for (int b = 0; b < NB_SCAN; ++b) {
            const int v = part[b];
            part[b] = run;
            run += v;
        }
    }
}

__global__ __launch_bounds__(256) void k_scanC(
    const int* __restrict__ deg, const int* __restrict__ part,
    int* __restrict__ offs, int* __restrict__ cursor)
{
    __shared__ int ts[256];
    const int t = threadIdx.x;
    const int base = blockIdx.x * SCAN_CHUNK + t * 4;
    int v[4]; int s = 0;
    #pragma unroll
    for (int i = 0; i < 4; ++i) {
        const int idx = base + i;
        v[i] = (idx < NN) ? deg[idx] : 0;
        s += v[i];
    }
    ts[t] = s;
    __syncthreads();
    for (int off = 1; off < 256; off <<= 1) {
        int val = ts[t];
        if (t >= off) val += ts[t - off];
        __syncthreads();
        ts[t] = val;
        __syncthreads();
    }
    int run = part[blockIdx.x] + ((t == 0) ? 0 : ts[t - 1]);
    #pragma unroll
    for (int i = 0; i < 4; ++i) {
        const int idx = base + i;
        if (idx < NN) { offs[idx] = run; cursor[idx] = run; run += v[i]; }
    }
}

// ---------------- k_fill2: CSR fill + Sea atomic segsum in ONE pass ----------------
// 16 edges/block, 16 lanes/edge. Lanes read ea[e] coalesced (64B/edge) and
// atomicAdd into Sea[r] (3.2MB, L2-scale); lane 0 does the cursor atomic and
// the csr write. Replaces k_fill (46us) + k_sea_se0's random gather (48us).
__global__ __launch_bounds__(256) void k_fill2(
    const float* __restrict__ ea, const int* __restrict__ send,
    const int* __restrict__ rec, int* __restrict__ cursor,
    int* __restrict__ csr, float* __restrict__ Sea)
{
    const int t = threadIdx.x;
    const int e = blockIdx.x * 16 + (t >> 4);
    const int c = t & 15;
    const int r = rec[e];
    atomicAdd(&Sea[(size_t)r * 16 + c], ea[(size_t)e * 16 + c]);
    if (c == 0) {
        const int pos = atomicAdd(&cursor[r], 1);
        csr[pos] = send[e];
    }
}

// ---------------- k_se0: Se0 = Sea @ Wee + deg * bee (dense, small) ----------------
__global__ __launch_bounds__(256) void k_se0(
    const float* __restrict__ Sea, const int* __restrict__ deg,
    const float* __restrict__ Wee, const float* __restrict__ bee,
    u16* __restrict__ Se)
{
    __shared__ float row[2][16];
    const int t = threadIdx.x;
    const int nl = t >> 7;
    const int col = t & 127;
    const int node = blockIdx.x * 2 + nl;
    if (col < 16) row[nl][col] = Sea[(size_t)node * 16 + col];
    __syncthreads();
    float acc = (float)deg[node] * bee[col];
    #pragma unroll
    for (int k = 0; k < 16; ++k) acc += row[nl][k] * Wee[k * 128 + col];
    Se[(size_t)node * 128 + col] = f2bf(acc);
}

// ---------------- k_gather ----------------
__global__ __launch_bounds__(256) void k_gather(
    const u16* __restrict__ h, const int* __restrict__ csr,
    const int* __restrict__ offs, const int* __restrict__ deg,
    u16* __restrict__ Sh)
{
    const int t = threadIdx.x;
    const int lane = t & 63;
    const int node = blockIdx.x * 4 + (t >> 6);     // grid 12500*4 = NN exact
    const int g = lane >> 4;
    const int l16 = lane & 15;
    const int off = offs[node];
    const int d = deg[node];
    const uint4* hp = (const uint4*)h;

    float a[8], b[8];
    #pragma unroll
    for (int i = 0; i < 8; ++i) { a[i] = 0.f; b[i] = 0.f; }

    int j = g;
    for (; j + 4 < d; j += 8) {
        const int s0 = csr[off + j];
        const int s1 = csr[off + j + 4];
        const uint4 v0 = hp[(size_t)s0 * 16 + l16];
        const uint4 v1 = hp[(size_t)s1 * 16 + l16];
        a[0] += bf2f((u16)(v0.x & 0xffff)); a[1] += bf2f((u16)(v0.x >> 16));
        a[2] += bf2f((u16)(v0.y & 0xffff)); a[3] += bf2f((u16)(v0.y >> 16));
        a[4] += bf2f((u16)(v0.z & 0xffff)); a[5] += bf2f((u16)(v0.z >> 16));
        a[6] += bf2f((u16)(v0.w & 0xffff)); a[7] += bf2f((u16)(v0.w >> 16));
        b[0] += bf2f((u16)(v1.x & 0xffff)); b[1] += bf2f((u16)(v1.x >> 16));
        b[2] += bf2f((u16)(v1.y & 0xffff)); b[3] += bf2f((u16)(v1.y >> 16));
        b[4] += bf2f((u16)(v1.z & 0xffff)); b[5] += bf2f((u16)(v1.z >> 16));
        b[6] += bf2f((u16)(v1.w & 0xffff)); b[7] += bf2f((u16)(v1.w >> 16));
    }
    if (j < d) {
        const uint4 v0 = hp[(size_t)csr[off + j] * 16 + l16];
        a[0] += bf2f((u16)(v0.x & 0xffff)); a[1] += bf2f((u16)(v0.x >> 16));
        a[2] += bf2f((u16)(v0.y & 0xffff)); a[3] += bf2f((u16)(v0.y >> 16));
        a[4] += bf2f((u16)(v0.z & 0xffff)); a[5] += bf2f((u16)(v0.z >> 16));
        a[6] += bf2f((u16)(v0.w & 0xffff)); a[7] += bf2f((u16)(v0.w >> 16));
    }
    #pragma unroll
    for (int i = 0; i < 8; ++i) {
        float s = a[i] + b[i];
        s += __shfl_xor(s, 16);
        s += __shfl_xor(s, 32);
        a[i] = s;
    }
    if (g == 0) {
        uint4 o;
        o.x = (u32)f2bf(a[0]) | ((u32)f2bf(a[1]) << 16);
        o.y = (u32)f2bf(a[2]) | ((u32)f2bf(a[3]) << 16);
        o.z = (u32)f2bf(a[4]) | ((u32)f2bf(a[5]) << 16);
        o.w = (u32)f2bf(a[6]) | ((u32)f2bf(a[7]) << 16);
        ((uint4*)Sh)[(size_t)node * 16 + l16] = o;
    }
}

// ---------------- k_dense v11 (r17, accepted plateau) ----------------
template<bool FULL>
__global__ __launch_bounds__(256, 2) void k_dense(
    const u16* __restrict__ h, const u16* __restrict__ Sh,
    const u16* __restrict__ Se, const int* __restrict__ deg,
    const u16* __restrict__ Bp, const float* __restrict__ cvec,
    const float* __restrict__ bh, const float* __restrict__ be,
    u16* __restrict__ h_out, u16* __restrict__ Se_out)
{
    const int t = threadIdx.x;
    const int lane = t & 63;
    const int w = t >> 6;
    if (!FULL && w >= 2) return;
    const int cb = w * 64;
    const bool isH = (cb < 128);           // wave-uniform
    const int rb = blockIdx.x * 32;
    const int l15 = lane & 15;
    const int kg  = lane >> 4;

    int r0 = rb + l15;      if (r0 > NN - 1) r0 = NN - 1;
    int r1 = rb + 16 + l15; if (r1 > NN - 1) r1 = NN - 1;

    #define BFRAG(ks, nf) (*(const short8v*)(Bp + \
        ((((size_t)(ks) * 4 + w) * 4 + kg) * 64 + (nf) * 16 + l15) * 8))

    f32x4 accP[2][4], accQ[2][4];
    #pragma unroll
    for (int m = 0; m < 2; ++m)
        #pragma unroll
        for (int n = 0; n < 4; ++n) {
            accP[m][n] = (f32x4){0.f, 0.f, 0.f, 0.f};
            accQ[m][n] = (f32x4){0.f, 0.f, 0.f, 0.f};
        }

    short8v ah0[4], ah1[4];                // h-frag cache (s==0 -> s==1 reuse)

    #pragma unroll
    for (int ks = 0; ks < 16; ++ks) {
        const int s = ks >> 2;             // compile-time under unroll
        const int k4 = ks & 3;
        const int ko = k4 * 32 + kg * 8;

        short8v a0, a1;
        bool active = true;
        if (s == 0) {
            if (isH) {
                a0 = *(const short8v*)(h + (size_t)r0 * 128 + ko);
                a1 = *(const short8v*)(h + (size_t)r1 * 128 + ko);
                ah0[k4] = a0; ah1[k4] = a1;
            } else {
                active = false;            // zero weight block -- skip
            }
        } else if (s == 1) {
            if (isH) { a0 = ah0[k4]; a1 = ah1[k4]; }
            else {
                a0 = *(const short8v*)(h + (size_t)r0 * 128 + ko);
                a1 = *(const short8v*)(h + (size_t)r1 * 128 + ko);
            }
        } else if (s == 2) {
            a0 = *(const short8v*)(Sh + (size_t)r0 * 128 + ko);
            a1 = *(const short8v*)(Sh + (size_t)r1 * 128 + ko);
        } else {
            a0 = *(const short8v*)(Se + (size_t)r0 * 128 + ko);
            a1 = *(const short8v*)(Se + (size_t)r1 * 128 + ko);
        }

        if (active) {
            #pragma unroll
            for (int nf = 0; nf < 4; ++nf) {
                const short8v b = BFRAG(ks, nf);
                if (s == 1) {
                    accQ[0][nf] = __builtin_amdgcn_mfma_f32_16x16x32_bf16(a0, b, accQ[0][nf], 0, 0, 0);
                    accQ[1][nf] = __builtin_amdgcn_mfma_f32_16x16x32_bf16(a1, b, accQ[1][nf], 0, 0, 0);
                } else {
                    accP[0][nf] = __builtin_amdgcn_mfma_f32_16x16x32_bf16(a0, b, accP[0][nf], 0, 0, 0);
                    accP[1][nf] = __builtin_amdgcn_mfma_f32_16x16x32_bf16(a1, b, accP[1][nf], 0, 0, 0);
                }
            }
        }
    }
    #undef BFRAG

    #pragma unroll
    for (int m = 0; m < 2; ++m) {
        #pragma unroll
        for (int r = 0; r < 4; ++r) {
            const int row = rb + m * 16 + kg * 4 + r;
            if (row < NN) {
                const float dg = (float)deg[row];
                if (cb < 128) {
                    #pragma unroll
                    for (int nf = 0; nf < 4; ++nf) {
                        const int col = cb + nf * 16 + l15;
                        h_out[(size_t)row * 128 + col] =
                            f2bf(accP[m][nf][r] + dg * accQ[m][nf][r] + bh[col] + dg * cvec[col]);
                    }
                } else {
                    #pragma unroll
                    for (int nf = 0; nf < 4; ++nf) {
                        const int col = cb - 128 + nf * 16 + l15;
                        Se_out[(size_t)row * 128 + col] =
                            f2bf(accP[m][nf][r] + dg * accQ[m][nf][r] + dg * be[col]);
                    }
                }
            }
        }
    }
}

// ---------------- k_pool ----------------
__global__ __launch_bounds__(256) void k_pool(
    const u16* __restrict__ h, const int* __restrict__ batch,
    float* __restrict__ out)
{
    const int t = threadIdx.x;
    const int col = t & 127;
    const int half = t >> 7;
    const int base = blockIdx.x * 64 + half * 32;
    float acc = 0.f;
    int curg = -1;
    for (int i = 0; i < 32; ++i) {
        const int n = base + i;
        if (n >= NN) break;
        const int g = batch[n];
        if (g != curg) {
            if (curg >= 0) atomicAdd(&out[curg * 128 + col], acc);
            curg = g; acc = 0.f;
        }
        acc += bf2f(h[(size_t)n * 128 + col]);
    }
    if (curg >= 0) atomicAdd(&out[curg * 128 + col], acc);
}

extern "C" void kernel_launch(void* const* d_in, const int* in_sizes, int n_in,
                              void* d_out, int out_size, void* d_ws, size_t ws_size,
                              hipStream_t stream)
{
    const float* x       = (const float*)d_in[0];
    const float* p       = (const float*)d_in[1];
    const float* ea      = (const float*)d_in[2];
    const int*   eidx    = (const int*)d_in[3];
    const int*   batch   = (const int*)d_in[4];
    const float* W_embed = (const float*)d_in[5];
    const float* b_embed = (const float*)d_in[6];
    const float* W_ee    = (const float*)d_in[7];
    const float* b_ee    = (const float*)d_in[8];
    const float* Wm      = (const float*)d_in[9];
    const float* bm      = (const float*)d_in[10];
    const float* Wh      = (const float*)d_in[11];
    const float* bh      = (const float*)d_in[12];
    const float* We      = (const float*)d_in[13];
    const float* be      = (const float*)d_in[14];
    const int* send = eidx;
    const int* rec  = eidx + NE;

    // ---- workspace layout (all chunks multiples of 16B) ----
    char* w = (char*)d_ws;
    const size_t NHb = (size_t)NN * 128 * sizeof(u16);     // 12.8 MB
    u16* hA  = (u16*)w; w += NHb;
    u16* hB  = (u16*)w; w += NHb;
    u16* SeA = (u16*)w; w += NHb;
    u16* SeB = (u16*)w; w += NHb;
    u16* Sh  = (u16*)w; w += NHb;
    u16* Axp = (u16*)w;  w += (size_t)NN * 96 * 2;         // 9.6 MB
    int*  deg    = (int*)w;   w += (size_t)NN * 4;
    int*  offs   = (int*)w;   w += (size_t)(NN + 4) * 4;
    int*  cursor = (int*)w;   w += (size_t)NN * 4;
    int*  csr    = (int*)w;   w += (size_t)NE * 4;
    float* Sea   = (float*)w; w += (size_t)NN * 16 * 4;    // 3.2 MB
    int*  part   = (int*)w;   w += 64 * 4;
    float* Wb    = (float*)w; w += (size_t)4 * 512 * 256 * 4;
    float* cvec  = (float*)w; w += 512 * 4;
    u16*  Bp     = (u16*)w;   w += (size_t)4 * 512 * 256 * 2;
    u16*  Wpe    = (u16*)w;   w += (size_t)3 * 128 * 32 * 2;
    const size_t need = (size_t)(w - (char*)d_ws);
    if (ws_size < need) {
        fprintf(stderr, "[kernel_launch] ws_size=%zu < needed=%zu — skipping\n",
                ws_size, need);
        return;
    }

    float* out = (float*)d_out;

    hipMemsetAsync(d_out, 0, (size_t)NG * 128 * sizeof(float), stream);
    hipMemsetAsync(deg, 0, (size_t)NN * sizeof(int), stream);
    hipMemsetAsync(Sea, 0, (size_t)NN * 16 * sizeof(float), stream);

    k_deg<<<NE / 256, 256, 0, stream>>>(rec, deg);
    k_prep_xp<<<NN * 48 / 256, 256, 0, stream>>>(x, p, Axp);
    k_wembed<<<3 * 128 * 32 / 256, 256, 0, stream>>>(W_embed, Wpe);
    k_embed<<<(NN + 127) / 128, 256, 0, stream>>>(Axp, Wpe, b_embed, hA);
    k_wprep<<<(4 * 512 * 256 + 512 + 255) / 256, 256, 0, stream>>>(Wm, Wh, We, bm, Wb, cvec);
    k_wswz<<<4 * 512 * 256 / 256, 256, 0, stream>>>(Wb, Bp);
    k_scanA<<<NB_SCAN, 256, 0, stream>>>(deg, part);
    k_scanB<<<1, 64, 0, stream>>>(part);
    k_scanC<<<NB_SCAN, 256, 0, stream>>>(deg, part, offs, cursor);
    k_fill2<<<NE / 16, 256, 0, stream>>>(ea, send, rec, cursor, csr, Sea);
    k_se0<<<NN / 2, 256, 0, stream>>>(Sea, deg, W_ee, b_ee, SeA);

    u16* h_cur = hA;   u16* h_nxt = hB;
    u16* Se_cur = SeA; u16* Se_nxt = SeB;
    for (int l = 0; l < NL; ++l) {
        k_gather<<<NN / 4, 256, 0, stream>>>(h_cur, csr, offs, deg, Sh);
        if (l < NL - 1)
            k_dense<true><<<(NN + 31) / 32, 256, 0, stream>>>(h_cur, Sh, Se_cur,
                deg, Bp + (size_t)l * 131072,
                cvec + l * 128, bh + l * 128, be + l * 128, h_nxt, Se_nxt);
        else
            k_dense<false><<<(NN + 31) / 32, 256, 0, stream>>>(h_cur, Sh, Se_cur,
                deg, Bp + (size_t)l * 131072,
                cvec + l * 128, bh + l * 128, be + l * 128, h_nxt, Se_nxt);
        u16* tmp;
        tmp = h_cur;  h_cur  = h_nxt;  h_nxt  = tmp;
        tmp = Se_cur; Se_cur = Se_nxt; Se_nxt = tmp;
    }
    k_pool<<<(NN + 63) / 64, 256, 0, stream>>>(h_cur, batch, out);
}

// Round 19
// 419.135 us; speedup vs baseline: 1.1260x; 1.1260x over previous
//
#include <hip/hip_runtime.h>
#include <cstdio>

#define NN 50000
#define NE 640000
#define NG 256
#define NL 4

#define SCAN_CHUNK 1024
#define NB_SCAN ((NN + SCAN_CHUNK - 1) / SCAN_CHUNK)   // 49

typedef unsigned short u16;
typedef unsigned int u32;
typedef __attribute__((ext_vector_type(8))) short short8v;   // 8 bf16 = 4 VGPR
typedef __attribute__((ext_vector_type(4))) float f32x4;

static __device__ __forceinline__ float bf2f(u16 v) {
    return __uint_as_float(((u32)v) << 16);
}
static __device__ __forceinline__ u16 f2bf(float f) {
    u32 u = __float_as_uint(f);
    u += 0x7fff + ((u >> 16) & 1);   // RNE
    return (u16)(u >> 16);
}

// ---------------- k_deg ----------------
__global__ __launch_bounds__(256) void k_deg(
    const int* __restrict__ rec, int* __restrict__ deg)
{
    const int e = blockIdx.x * 256 + threadIdx.x;
    atomicAdd(&deg[rec[e]], 1);
}

// ---------------- k_prep_xp ----------------
__global__ __launch_bounds__(256) void k_prep_xp(
    const float* __restrict__ x, const float* __restrict__ p,
    u16* __restrict__ Axp)
{
    const int idx = blockIdx.x * 256 + threadIdx.x;   // NN*48 u32s
    const int row = idx / 48;
    const int c2 = idx - row * 48;
    const int c0 = c2 * 2;
    float f0, f1;
    if (c0 < 64)      { f0 = x[(size_t)row * 64 + c0]; f1 = x[(size_t)row * 64 + c0 + 1]; }
    else if (c0 < 80) { f0 = p[(size_t)row * 16 + c0 - 64]; f1 = p[(size_t)row * 16 + c0 - 63]; }
    else              { f0 = 0.f; f1 = 0.f; }
    ((u32*)Axp)[idx] = (u32)f2bf(f0) | ((u32)f2bf(f1) << 16);
}

// ---------------- k_wembed: [ks][col][32] ----------------
__global__ __launch_bounds__(256) void k_wembed(
    const float* __restrict__ W, u16* __restrict__ Wp)
{
    const int idx = blockIdx.x * 256 + threadIdx.x;   // 3*128*32
    const int ks = idx >> 12;
    const int rem = idx & 4095;
    const int col = rem >> 5;
    const int kk = rem & 31;
    const int k = ks * 32 + kk;
    Wp[((size_t)ks * 128 + col) * 32 + kk] = f2bf(k < 80 ? W[k * 128 + col] : 0.f);
}

// ---------------- k_embed ----------------
__global__ __launch_bounds__(256) void k_embed(
    const u16* __restrict__ Axp, const u16* __restrict__ Wp,
    const float* __restrict__ b, u16* __restrict__ h)
{
    const int t = threadIdx.x;
    const int lane = t & 63;
    const int w = t >> 6;
    const int rb = blockIdx.x * 128 + w * 32;
    const int l15 = lane & 15;
    const int kg  = lane >> 4;

    int r0 = rb + l15;      if (r0 > NN - 1) r0 = NN - 1;
    int r1 = rb + 16 + l15; if (r1 > NN - 1) r1 = NN - 1;

    f32x4 acc[2][8];
    #pragma unroll
    for (int m = 0; m < 2; ++m)
        #pragma unroll
        for (int n = 0; n < 8; ++n) acc[m][n] = (f32x4){0.f, 0.f, 0.f, 0.f};

    #pragma unroll
    for (int ks = 0; ks < 3; ++ks) {
        const short8v a0 = *(const short8v*)(Axp + (size_t)r0 * 96 + ks * 32 + kg * 8);
        const short8v a1 = *(const short8v*)(Axp + (size_t)r1 * 96 + ks * 32 + kg * 8);
        const u16* bb = Wp + ((size_t)ks * 128 + l15) * 32 + kg * 8;
        #pragma unroll
        for (int nf = 0; nf < 8; ++nf) {
            const short8v bv = *(const short8v*)(bb + (size_t)nf * 16 * 32);
            acc[0][nf] = __builtin_amdgcn_mfma_f32_16x16x32_bf16(a0, bv, acc[0][nf], 0, 0, 0);
            acc[1][nf] = __builtin_amdgcn_mfma_f32_16x16x32_bf16(a1, bv, acc[1][nf], 0, 0, 0);
        }
    }

    #pragma unroll
    for (int m = 0; m < 2; ++m) {
        #pragma unroll
        for (int r = 0; r < 4; ++r) {
            const int row = rb + m * 16 + kg * 4 + r;
            if (row < NN) {
                #pragma unroll
                for (int nf = 0; nf < 8; ++nf) {
                    const int col = nf * 16 + l15;
                    h[(size_t)row * 128 + col] = f2bf(acc[m][nf][r] + b[col]);
                }
            }
        }
    }
}

// ---------------- k_wprep: Wb fp32 [l][512][256] + cvec ----------------
__global__ __launch_bounds__(256) void k_wprep(
    const float* __restrict__ Wm, const float* __restrict__ Wh,
    const float* __restrict__ We, const float* __restrict__ bm,
    float* __restrict__ Wb, float* __restrict__ cvec)
{
    const int idx = blockIdx.x * 256 + threadIdx.x;
    const int total = 4 * 512 * 256;
    if (idx < total) {
        const int l = idx >> 17;
        const int rem = idx & 131071;
        const int k = rem >> 8;
        const int c = rem & 255;
        const float* Wm_l = Wm + (size_t)l * 384 * 128;
        const float* Wh_l = Wh + (size_t)l * 256 * 128;
        const float* We_l = We + (size_t)l * 384 * 128;
        float v;
        if (k < 128) {
            v = (c < 128) ? Wh_l[k * 128 + c] : 0.f;
        } else {
            const int kk  = (k - 128) & 127;
            const int blk = (k - 128) >> 7;               // 0:dh 1:Sh 2:Se
            const int roff = (blk == 0) ? 128 : (blk == 1) ? 0 : 256;
            if (c < 128) {
                float s = 0.f;
                #pragma unroll 4
                for (int j = 0; j < 128; ++j)
                    s += Wm_l[(roff + kk) * 128 + j] * Wh_l[(128 + j) * 128 + c];
                v = s;
            } else {
                v = We_l[(roff + kk) * 128 + (c - 128)];
            }
        }
        Wb[idx] = v;
    } else if (idx < total + 512) {
        const int r = idx - total;
        const int l = r >> 7;
        const int c = r & 127;
        const float* Wh_l = Wh + (size_t)l * 256 * 128;
        const float* bm_l = bm + l * 128;
        float s = 0.f;
        #pragma unroll 4
        for (int j = 0; j < 128; ++j) s += bm_l[j] * Wh_l[(128 + j) * 128 + c];
        cvec[r] = s;
    }
}

// ---------------- k_wswz: Wb -> Bp bf16 [l][ks][cg64][kg][n64][8] ----------------
__global__ __launch_bounds__(256) void k_wswz(
    const float* __restrict__ Wb, u16* __restrict__ Bp)
{
    const int idx = blockIdx.x * 256 + threadIdx.x;    // 4*512*256
    const int l = idx >> 17;
    const int rem = idx & 131071;
    const int k = rem >> 8;
    const int n = rem & 255;
    const int ks = k >> 5;
    const int kg = (k >> 3) & 3;
    const int kk = k & 7;
    const int cg = n >> 6;
    const int n64 = n & 63;
    Bp[(size_t)l * 131072 +
       ((((size_t)ks * 4 + cg) * 4 + kg) * 64 + n64) * 8 + kk] = f2bf(Wb[idx]);
}

// ---------------- scan (3 phases) ----------------
__global__ __launch_bounds__(256) void k_scanA(
    const int* __restrict__ deg, int* __restrict__ part)
{
    __shared__ int red[256];
    const int t = threadIdx.x;
    const int base = blockIdx.x * SCAN_CHUNK + t * 4;
    int s = 0;
    #pragma unroll
    for (int i = 0; i < 4; ++i) {
        const int idx = base + i;
        if (idx < NN) s += deg[idx];
    }
    red[t] = s;
    __syncthreads();
    for (int off = 128; off > 0; off >>= 1) {
        if (t < off) red[t] += red[t + off];
        __syncthreads();
    }
    if (t == 0) part[blockIdx.x] = red[0];
}

__global__ __launch_bounds__(64) void k_scanB(int* part)
{
    if (threadIdx.x == 0) {
        int run = 0;
        for (int b = 0; b < NB_SCAN; ++b) {
            const int v = part[b];
            part[b] = run;
            run += v;
        }
    }
}

__global__ __launch_bounds__(256) void k_scanC(
    const int* __restrict__ deg, const int* __restrict__ part,
    int* __restrict__ offs, int* __restrict__ cursor)
{
    __shared__ int ts[256];
    const int t = threadIdx.x;
    const int base = blockIdx.x * SCAN_CHUNK + t * 4;
    int v[4]; int s = 0;
    #pragma unroll
    for (int i = 0; i < 4; ++i) {
        const int idx = base + i;
        v[i] = (idx < NN) ? deg[idx] : 0;
        s += v[i];
    }
    ts[t] = s;
    __syncthreads();
    for (int off = 1; off < 256; off <<= 1) {
        int val = ts[t];
        if (t >= off) val += ts[t - off];
        __syncthreads();
        ts[t] = val;
        __syncthreads();
    }
    int run = part[blockIdx.x] + ((t == 0) ? 0 : ts[t - 1]);
    #pragma unroll
    for (int i = 0; i < 4; ++i) {
        const int idx = base + i;
        if (idx < NN) { offs[idx] = run; cursor[idx] = run; run += v[i]; }
    }
}

// ---------------- k_fill: ONE scattered 8B write per edge: csr2[pos] = (send, e) ----------------
// r17's two scattered 4B streams (csr, csr_e) touched two dirty lines per
// edge -> 69MB writeback for 5MB payload. Combining halves the line visits.
__global__ __launch_bounds__(256) void k_fill(
    const int* __restrict__ send, const int* __restrict__ rec,
    int* __restrict__ cursor, int2* __restrict__ csr2)
{
    const int e = blockIdx.x * 256 + threadIdx.x;
    const int r = rec[e];
    const int pos = atomicAdd(&cursor[r], 1);
    csr2[pos] = make_int2(send[e], e);
}

// ---------------- k_sea_se0: CSR gather of ea (2-deep ILP) + fused Se0 GEMM ----------------
__global__ __launch_bounds__(256) void k_sea_se0(
    const float* __restrict__ ea, const int2* __restrict__ csr2,
    const int* __restrict__ offs, const int* __restrict__ deg,
    const float* __restrict__ Wee, const float* __restrict__ bee,
    u16* __restrict__ Se)
{
    __shared__ float sea[4][16];
    const int t = threadIdx.x;
    const int lane = t & 63;
    const int w = t >> 6;
    const int nb = blockIdx.x * 4;
    const int node = nb + w;
    const int g = lane >> 4;
    const int l16 = lane & 15;
    const int off = offs[node];
    const int d = deg[node];

    float acc0 = 0.f, acc1 = 0.f;
    int j = g;
    for (; j + 4 < d; j += 8) {
        const int e0 = csr2[off + j].y;
        const int e1 = csr2[off + j + 4].y;
        acc0 += ea[(size_t)e0 * 16 + l16];
        acc1 += ea[(size_t)e1 * 16 + l16];
    }
    if (j < d) acc0 += ea[(size_t)csr2[off + j].y * 16 + l16];
    float acc = acc0 + acc1;
    acc += __shfl_xor(acc, 16);
    acc += __shfl_xor(acc, 32);
    if (g == 0) sea[w][l16] = acc;
    __syncthreads();

    const int c = t & 127;
    #pragma unroll
    for (int q = 0; q < 2; ++q) {
        const int n = (t >> 7) + 2 * q;
        const int nd = nb + n;
        float a = (float)deg[nd] * bee[c];
        #pragma unroll
        for (int k = 0; k < 16; ++k) a += sea[n][k] * Wee[k * 128 + c];
        Se[(size_t)nd * 128 + c] = f2bf(a);
    }
}

// ---------------- k_gather ----------------
__global__ __launch_bounds__(256) void k_gather(
    const u16* __restrict__ h, const int2* __restrict__ csr2,
    const int* __restrict__ offs, const int* __restrict__ deg,
    u16* __restrict__ Sh)
{
    const int t = threadIdx.x;
    const int lane = t & 63;
    const int node = blockIdx.x * 4 + (t >> 6);     // grid 12500*4 = NN exact
    const int g = lane >> 4;
    const int l16 = lane & 15;
    const int off = offs[node];
    const int d = deg[node];
    const uint4* hp = (const uint4*)h;

    float a[8], b[8];
    #pragma unroll
    for (int i = 0; i < 8; ++i) { a[i] = 0.f; b[i] = 0.f; }

    int j = g;
    for (; j + 4 < d; j += 8) {
        const int s0 = csr2[off + j].x;
        const int s1 = csr2[off + j + 4].x;
        const uint4 v0 = hp[(size_t)s0 * 16 + l16];
        const uint4 v1 = hp[(size_t)s1 * 16 + l16];
        a[0] += bf2f((u16)(v0.x & 0xffff)); a[1] += bf2f((u16)(v0.x >> 16));
        a[2] += bf2f((u16)(v0.y & 0xffff)); a[3] += bf2f((u16)(v0.y >> 16));
        a[4] += bf2f((u16)(v0.z & 0xffff)); a[5] += bf2f((u16)(v0.z >> 16));
        a[6] += bf2f((u16)(v0.w & 0xffff)); a[7] += bf2f((u16)(v0.w >> 16));
        b[0] += bf2f((u16)(v1.x & 0xffff)); b[1] += bf2f((u16)(v1.x >> 16));
        b[2] += bf2f((u16)(v1.y & 0xffff)); b[3] += bf2f((u16)(v1.y >> 16));
        b[4] += bf2f((u16)(v1.z & 0xffff)); b[5] += bf2f((u16)(v1.z >> 16));
        b[6] += bf2f((u16)(v1.w & 0xffff)); b[7] += bf2f((u16)(v1.w >> 16));
    }
    if (j < d) {
        const uint4 v0 = hp[(size_t)csr2[off + j].x * 16 + l16];
        a[0] += bf2f((u16)(v0.x & 0xffff)); a[1] += bf2f((u16)(v0.x >> 16));
        a[2] += bf2f((u16)(v0.y & 0xffff)); a[3] += bf2f((u16)(v0.y >> 16));
        a[4] += bf2f((u16)(v0.z & 0xffff)); a[5] += bf2f((u16)(v0.z >> 16));
        a[6] += bf2f((u16)(v0.w & 0xffff)); a[7] += bf2f((u16)(v0.w >> 16));
    }
    #pragma unroll
    for (int i = 0; i < 8; ++i) {
        float s = a[i] + b[i];
        s += __shfl_xor(s, 16);
        s += __shfl_xor(s, 32);
        a[i] = s;
    }
    if (g == 0) {
        uint4 o;
        o.x = (u32)f2bf(a[0]) | ((u32)f2bf(a[1]) << 16);
        o.y = (u32)f2bf(a[2]) | ((u32)f2bf(a[3]) << 16);
        o.z = (u32)f2bf(a[4]) | ((u32)f2bf(a[5]) << 16);
        o.w = (u32)f2bf(a[6]) | ((u32)f2bf(a[7]) << 16);
        ((uint4*)Sh)[(size_t)node * 16 + l16] = o;
    }
}

// ---------------- k_dense v11 (r17, accepted plateau) ----------------
template<bool FULL>
__global__ __launch_bounds__(256, 2) void k_dense(
    const u16* __restrict__ h, const u16* __restrict__ Sh,
    const u16* __restrict__ Se, const int* __restrict__ deg,
    const u16* __restrict__ Bp, const float* __restrict__ cvec,
    const float* __restrict__ bh, const float* __restrict__ be,
    u16* __restrict__ h_out, u16* __restrict__ Se_out)
{
    const int t = threadIdx.x;
    const int lane = t & 63;
    const int w = t >> 6;
    if (!FULL && w >= 2) return;
    const int cb = w * 64;
    const bool isH = (cb < 128);           // wave-uniform
    const int rb = blockIdx.x * 32;
    const int l15 = lane & 15;
    const int kg  = lane >> 4;

    int r0 = rb + l15;      if (r0 > NN - 1) r0 = NN - 1;
    int r1 = rb + 16 + l15; if (r1 > NN - 1) r1 = NN - 1;

    #define BFRAG(ks, nf) (*(const short8v*)(Bp + \
        ((((size_t)(ks) * 4 + w) * 4 + kg) * 64 + (nf) * 16 + l15) * 8))

    f32x4 accP[2][4], accQ[2][4];
    #pragma unroll
    for (int m = 0; m < 2; ++m)
        #pragma unroll
        for (int n = 0; n < 4; ++n) {
            accP[m][n] = (f32x4){0.f, 0.f, 0.f, 0.f};
            accQ[m][n] = (f32x4){0.f, 0.f, 0.f, 0.f};
        }

    short8v ah0[4], ah1[4];                // h-frag cache (s==0 -> s==1 reuse)

    #pragma unroll
    for (int ks = 0; ks < 16; ++ks) {
        const int s = ks >> 2;             // compile-time under unroll
        const int k4 = ks & 3;
        const int ko = k4 * 32 + kg * 8;

        short8v a0, a1;
        bool active = true;
        if (s == 0) {
            if (isH) {
                a0 = *(const short8v*)(h + (size_t)r0 * 128 + ko);
                a1 = *(const short8v*)(h + (size_t)r1 * 128 + ko);
                ah0[k4] = a0; ah1[k4] = a1;
            } else {
                active = false;            // zero weight block -- skip
            }
        } else if (s == 1) {
            if (isH) { a0 = ah0[k4]; a1 = ah1[k4]; }
            else {
                a0 = *(const short8v*)(h + (size_t)r0 * 128 + ko);
                a1 = *(const short8v*)(h + (size_t)r1 * 128 + ko);
            }
        } else if (s == 2) {
            a0 = *(const short8v*)(Sh + (size_t)r0 * 128 + ko);
            a1 = *(const short8v*)(Sh + (size_t)r1 * 128 + ko);
        } else {
            a0 = *(const short8v*)(Se + (size_t)r0 * 128 + ko);
            a1 = *(const short8v*)(Se + (size_t)r1 * 128 + ko);
        }

        if (active) {
            #pragma unroll
            for (int nf = 0; nf < 4; ++nf) {
                const short8v b = BFRAG(ks, nf);
                if (s == 1) {
                    accQ[0][nf] = __builtin_amdgcn_mfma_f32_16x16x32_bf16(a0, b, accQ[0][nf], 0, 0, 0);
                    accQ[1][nf] = __builtin_amdgcn_mfma_f32_16x16x32_bf16(a1, b, accQ[1][nf], 0, 0, 0);
                } else {
                    accP[0][nf] = __builtin_amdgcn_mfma_f32_16x16x32_bf16(a0, b, accP[0][nf], 0, 0, 0);
                    accP[1][nf] = __builtin_amdgcn_mfma_f32_16x16x32_bf16(a1, b, accP[1][nf], 0, 0, 0);
                }
            }
        }
    }
    #undef BFRAG

    #pragma unroll
    for (int m = 0; m < 2; ++m) {
        #pragma unroll
        for (int r = 0; r < 4; ++r) {
            const int row = rb + m * 16 + kg * 4 + r;
            if (row < NN) {
                const float dg = (float)deg[row];
                if (cb < 128) {
                    #pragma unroll
                    for (int nf = 0; nf < 4; ++nf) {
                        const int col = cb + nf * 16 + l15;
                        h_out[(size_t)row * 128 + col] =
                            f2bf(accP[m][nf][r] + dg * accQ[m][nf][r] + bh[col] + dg * cvec[col]);
                    }
                } else {
                    #pragma unroll
                    for (int nf = 0; nf < 4; ++nf) {
                        const int col = cb - 128 + nf * 16 + l15;
                        Se_out[(size_t)row * 128 + col] =
                            f2bf(accP[m][nf][r] + dg * accQ[m][nf][r] + dg * be[col]);
                    }
                }
            }
        }
    }
}

// ---------------- k_pool ----------------
__global__ __launch_bounds__(256) void k_pool(
    const u16* __restrict__ h, const int* __restrict__ batch,
    float* __restrict__ out)
{
    const int t = threadIdx.x;
    const int col = t & 127;
    const int half = t >> 7;
    const int base = blockIdx.x * 64 + half * 32;
    float acc = 0.f;
    int curg = -1;
    for (int i = 0; i < 32; ++i) {
        const int n = base + i;
        if (n >= NN) break;
        const int g = batch[n];
        if (g != curg) {
            if (curg >= 0) atomicAdd(&out[curg * 128 + col], acc);
            curg = g; acc = 0.f;
        }
        acc += bf2f(h[(size_t)n * 128 + col]);
    }
    if (curg >= 0) atomicAdd(&out[curg * 128 + col], acc);
}

extern "C" void kernel_launch(void* const* d_in, const int* in_sizes, int n_in,
                              void* d_out, int out_size, void* d_ws, size_t ws_size,
                              hipStream_t stream)
{
    const float* x       = (const float*)d_in[0];
    const float* p       = (const float*)d_in[1];
    const float* ea      = (const float*)d_in[2];
    const int*   eidx    = (const int*)d_in[3];
    const int*   batch   = (const int*)d_in[4];
    const float* W_embed = (const float*)d_in[5];
    const float* b_embed = (const float*)d_in[6];
    const float* W_ee    = (const float*)d_in[7];
    const float* b_ee    = (const float*)d_in[8];
    const float* Wm      = (const float*)d_in[9];
    const float* bm      = (const float*)d_in[10];
    const float* Wh      = (const float*)d_in[11];
    const float* bh      = (const float*)d_in[12];
    const float* We      = (const float*)d_in[13];
    const float* be      = (const float*)d_in[14];
    const int* send = eidx;
    const int* rec  = eidx + NE;

    // ---- workspace layout (all chunks multiples of 16B) ----
    char* w = (char*)d_ws;
    const size_t NHb = (size_t)NN * 128 * sizeof(u16);     // 12.8 MB
    u16* hA  = (u16*)w; w += NHb;
    u16* hB  = (u16*)w; w += NHb;
    u16* SeA = (u16*)w; w += NHb;
    u16* SeB = (u16*)w; w += NHb;
    u16* Sh  = (u16*)w; w += NHb;
    u16* Axp = (u16*)w;  w += (size_t)NN * 96 * 2;         // 9.6 MB
    int*  deg    = (int*)w;   w += (size_t)NN * 4;
    int*  offs   = (int*)w;   w += (size_t)(NN + 4) * 4;
    int*  cursor = (int*)w;   w += (size_t)NN * 4;
    int2* csr2   = (int2*)w;  w += (size_t)NE * 8;
    int*  part   = (int*)w;   w += 64 * 4;
    float* Wb    = (float*)w; w += (size_t)4 * 512 * 256 * 4;
    float* cvec  = (float*)w; w += 512 * 4;
    u16*  Bp     = (u16*)w;   w += (size_t)4 * 512 * 256 * 2;
    u16*  Wpe    = (u16*)w;   w += (size_t)3 * 128 * 32 * 2;
    const size_t need = (size_t)(w - (char*)d_ws);
    if (ws_size < need) {
        fprintf(stderr, "[kernel_launch] ws_size=%zu < needed=%zu — skipping\n",
                ws_size, need);
        return;
    }

    float* out = (float*)d_out;

    hipMemsetAsync(d_out, 0, (size_t)NG * 128 * sizeof(float), stream);
    hipMemsetAsync(deg, 0, (size_t)NN * sizeof(int), stream);

    k_deg<<<NE / 256, 256, 0, stream>>>(rec, deg);
    k_prep_xp<<<NN * 48 / 256, 256, 0, stream>>>(x, p, Axp);
    k_wembed<<<3 * 128 * 32 / 256, 256, 0, stream>>>(W_embed, Wpe);
    k_embed<<<(NN + 127) / 128, 256, 0, stream>>>(Axp, Wpe, b_embed, hA);
    k_wprep<<<(4 * 512 * 256 + 512 + 255) / 256, 256, 0, stream>>>(Wm, Wh, We, bm, Wb, cvec);
    k_wswz<<<4 * 512 * 256 / 256, 256, 0, stream>>>(Wb, Bp);
    k_scanA<<<NB_SCAN, 256, 0, stream>>>(deg, part);
    k_scanB<<<1, 64, 0, stream>>>(part);
    k_scanC<<<NB_SCAN, 256, 0, stream>>>(deg, part, offs, cursor);
    k_fill<<<NE / 256, 256, 0, stream>>>(send, rec, cursor, csr2);
    k_sea_se0<<<NN / 4, 256, 0, stream>>>(ea, csr2, offs, deg, W_ee, b_ee, SeA);

    u16* h_cur = hA;   u16* h_nxt = hB;
    u16* Se_cur = SeA; u16* Se_nxt = SeB;
    for (int l = 0; l < NL; ++l) {
        k_gather<<<NN / 4, 256, 0, stream>>>(h_cur, csr2, offs, deg, Sh);
        if (l < NL - 1)
            k_dense<true><<<(NN + 31) / 32, 256, 0, stream>>>(h_cur, Sh, Se_cur,
                deg, Bp + (size_t)l * 131072,
                cvec + l * 128, bh + l * 128, be + l * 128, h_nxt, Se_nxt);
        else
            k_dense<false><<<(NN + 31) / 32, 256, 0, stream>>>(h_cur, Sh, Se_cur,
                deg, Bp + (size_t)l * 131072,
                cvec + l * 128, bh + l * 128, be + l * 128, h_nxt, Se_nxt);
        u16* tmp;
        tmp = h_cur;  h_cur  = h_nxt;  h_nxt  = tmp;
        tmp = Se_cur; Se_cur = Se_nxt; Se_nxt = tmp;
    }
    k_pool<<<(NN + 63) / 64, 256, 0, stream>>>(h_cur, batch, out);
}